// Round 3
// baseline (280.645 us; speedup 1.0000x reference)
//
#include <hip/hip_runtime.h>
#include <math.h>

// Problem sizes (fixed by setup_inputs)
constexpr int BATCH = 64;
constexpr int IN    = 1024;
constexpr int NN    = 2048;   // num_neurons
constexpr int OUTF  = 1024;

constexpr float SCALE   = 651.8986469044033f;   // 4096 / (2*pi)
constexpr float INV4096 = 2.44140625e-4f;       // 1/4096
constexpr float SQRT2   = 1.4142135623730951f;

// ---------------- Stage 1: interference ----------------
constexpr int KSPLIT = 2;              // k-slabs -> 2 partial buffers
constexpr int KRANGE = IN / KSPLIT;    // 512 k per block
constexpr int KC     = 256;            // staged k-chunk (one wave-row = 1024B)
constexpr int PAD    = 260;            // LDS row stride: 16B-aligned, odd*4 -> conflict-free reads

// part[kslab][n][b]  (2 * 2048 * 64 floats = 1 MiB in ws)

__global__ __launch_bounds__(256, 4)
void k_interf(const float* __restrict__ x, const float* __restrict__ W,
              const float* __restrict__ B, float* __restrict__ part) {
    __shared__ float xs[32 * PAD];   // 32 batch-rows x 256 k (padded) = 33.3 KB

    const int tid   = threadIdx.x;
    const int lane  = tid & 63;
    const int wv    = __builtin_amdgcn_readfirstlane(tid >> 6);   // wave id, scalar
    const int bid   = blockIdx.x;               // 1024 blocks
    const int kslab = bid & (KSPLIT - 1);
    const int n     = (bid >> 1) * 4 + wv;      // neuron handled by this wave
    const int k0    = kslab * KRANGE;
    const int r0    = wv * 8;                   // this wave stages rows r0..r0+7

#pragma unroll
    for (int h = 0; h < 2; ++h) {               // batch halves -> acc[32] only (no spill)
        float acc[32];
#pragma unroll
        for (int b = 0; b < 32; ++b) acc[b] = 0.0f;

#pragma unroll
        for (int kc = 0; kc < KRANGE; kc += KC) {
            const int kb = k0 + kc;

            // per-lane prep for 4 k values: inv = SCALE/(1+|W|), bsc = B*SCALE
            const float4 w4 = *(const float4*)&W[(size_t)n * IN + kb + 4 * lane];
            const float4 b4 = *(const float4*)&B[(size_t)n * IN + kb + 4 * lane];
            float4 inv, bsc;
            inv.x = SCALE * __builtin_amdgcn_rcpf(1.0f + fabsf(w4.x));
            inv.y = SCALE * __builtin_amdgcn_rcpf(1.0f + fabsf(w4.y));
            inv.z = SCALE * __builtin_amdgcn_rcpf(1.0f + fabsf(w4.z));
            inv.w = SCALE * __builtin_amdgcn_rcpf(1.0f + fabsf(w4.w));
            bsc.x = b4.x * SCALE;
            bsc.y = b4.y * SCALE;
            bsc.z = b4.z * SCALE;
            bsc.w = b4.w * SCALE;

            __syncthreads();   // protect xs from previous chunk's readers
            {
                // async global->LDS, zero VGPR temps: one wave-issue per row
                const float* gx = x + (size_t)(h * 32) * IN + kb;
#pragma unroll
                for (int rr = 0; rr < 8; ++rr) {
                    const int r = r0 + rr;
                    __builtin_amdgcn_global_load_lds(
                        (const __attribute__((address_space(1))) unsigned int*)
                            (gx + (size_t)r * IN + 4 * lane),
                        (__attribute__((address_space(3))) unsigned int*)&xs[r * PAD],
                        16, 0, 0);
                }
            }
            __syncthreads();   // drains vmcnt (global_load_lds) before reads

#pragma unroll
            for (int bb = 0; bb < 32; ++bb) {
                const float4 xv = *(const float4*)&xs[bb * PAD + 4 * lane];
                // s = theta*SCALE ; quantized angle (revolutions) = rint(s)/4096 ; +1/8 rev = +pi/4
                const float s0 = fmaf(xv.x, inv.x, bsc.x);
                const float s1 = fmaf(xv.y, inv.y, bsc.y);
                const float s2 = fmaf(xv.z, inv.z, bsc.z);
                const float s3 = fmaf(xv.w, inv.w, bsc.w);
                const float a0 = fmaf(__builtin_rintf(s0), INV4096, 0.125f);
                const float a1 = fmaf(__builtin_rintf(s1), INV4096, 0.125f);
                const float a2 = fmaf(__builtin_rintf(s2), INV4096, 0.125f);
                const float a3 = fmaf(__builtin_rintf(s3), INV4096, 0.125f);
                const float t0 = __builtin_amdgcn_sinf(a0);   // sin(2*pi*a)
                const float t1 = __builtin_amdgcn_sinf(a1);
                const float t2 = __builtin_amdgcn_sinf(a2);
                const float t3 = __builtin_amdgcn_sinf(a3);
                acc[bb] += (t0 + t1) + (t2 + t3);
            }
        }

        // cross-lane transpose-reduction, 32 values over 64 lanes.
        // Fold the half-wave first: lanes l and l^32 hold identical batch sets after this.
#pragma unroll
        for (int j = 0; j < 32; ++j) acc[j] += __shfl_xor(acc[j], 32, 64);
#pragma unroll
        for (int m = 16; m >= 1; m >>= 1) {
            const bool hi = (lane & m) != 0;
#pragma unroll
            for (int j = 0; j < m; ++j) {
                const float send = hi ? acc[j] : acc[j + m];
                const float recv = __shfl_xor(send, m, 64);
                acc[j] = (hi ? acc[j + m] : acc[j]) + recv;
            }
        }
        if (lane < 32)   // lane l holds batch h*32 + l
            part[((size_t)kslab * NN + n) * 64 + h * 32 + lane] = acc[0] * SQRT2;
    }
}

// ---------------- Stage 2: projection ----------------
// Block computes [64 b x 16 o] over NN/NSPLIT n, LDS-staged part, no atomics
// (atomic fallback if ws is small). grid = 64 o-tiles * NSPLIT.

template<int NSPLIT, bool ATOMIC>
__global__ __launch_bounds__(256, 4)
void k_proj(const float* __restrict__ part, const float* __restrict__ ow,
            float* __restrict__ dst) {
    __shared__ float xs[64 * 64];   // [nn][b], 16 KB

    const int tid  = threadIdx.x;
    const int lane = tid & 63;                                   // = batch b
    const int og   = __builtin_amdgcn_readfirstlane(tid >> 6);   // wave-uniform
    const int bid  = blockIdx.x;
    const int ns   = bid % NSPLIT;
    const int ot   = bid / NSPLIT;                               // 0..63
    const int o0   = ot * 16 + og * 4;
    const int NR   = NN / NSPLIT;
    const int n0   = ns * NR;

    float a0 = 0.f, a1 = 0.f, a2 = 0.f, a3 = 0.f;

    for (int c = 0; c < NR; c += 64) {
        const int nb = n0 + c;
        __syncthreads();
        {   // stage 64n x 64b, summing the two k-slabs
            const float4* s0 = (const float4*)(part + (size_t)nb * 64);
            const float4* s1 = (const float4*)(part + (size_t)NN * 64 + (size_t)nb * 64);
            float4* xd = (float4*)xs;
#pragma unroll
            for (int r = 0; r < 4; ++r) {
                const int j = tid + 256 * r;
                const float4 u = s0[j];
                const float4 v = s1[j];
                float4 s; s.x = u.x + v.x; s.y = u.y + v.y; s.z = u.z + v.z; s.w = u.w + v.w;
                xd[j] = s;
            }
        }
        __syncthreads();

        const float* w0 = ow + (size_t)(o0 + 0) * NN + nb;
        const float* w1 = ow + (size_t)(o0 + 1) * NN + nb;
        const float* w2 = ow + (size_t)(o0 + 2) * NN + nb;
        const float* w3 = ow + (size_t)(o0 + 3) * NN + nb;
#pragma unroll 4
        for (int nn = 0; nn < 64; nn += 4) {
            const float4 wa = *(const float4*)(w0 + nn);
            const float4 wb = *(const float4*)(w1 + nn);
            const float4 wc = *(const float4*)(w2 + nn);
            const float4 wd = *(const float4*)(w3 + nn);
            const float v0 = xs[(nn + 0) * 64 + lane];
            const float v1 = xs[(nn + 1) * 64 + lane];
            const float v2 = xs[(nn + 2) * 64 + lane];
            const float v3 = xs[(nn + 3) * 64 + lane];
            a0 = fmaf(v0, wa.x, a0); a0 = fmaf(v1, wa.y, a0);
            a0 = fmaf(v2, wa.z, a0); a0 = fmaf(v3, wa.w, a0);
            a1 = fmaf(v0, wb.x, a1); a1 = fmaf(v1, wb.y, a1);
            a1 = fmaf(v2, wb.z, a1); a1 = fmaf(v3, wb.w, a1);
            a2 = fmaf(v0, wc.x, a2); a2 = fmaf(v1, wc.y, a2);
            a2 = fmaf(v2, wc.z, a2); a2 = fmaf(v3, wc.w, a2);
            a3 = fmaf(v0, wd.x, a3); a3 = fmaf(v1, wd.y, a3);
            a3 = fmaf(v2, wd.z, a3); a3 = fmaf(v3, wd.w, a3);
        }
    }

    if (ATOMIC) {
        atomicAdd(&dst[(size_t)lane * OUTF + o0 + 0], a0);
        atomicAdd(&dst[(size_t)lane * OUTF + o0 + 1], a1);
        atomicAdd(&dst[(size_t)lane * OUTF + o0 + 2], a2);
        atomicAdd(&dst[(size_t)lane * OUTF + o0 + 3], a3);
    } else {
        float4 r; r.x = a0; r.y = a1; r.z = a2; r.w = a3;
        *(float4*)&dst[((size_t)ns * 64 + lane) * OUTF + o0] = r;
    }
}

template<int NSPLIT>
__global__ __launch_bounds__(256)
void k_reduce(const float* __restrict__ partial, float* __restrict__ out) {
    const int idx = blockIdx.x * 256 + threadIdx.x;   // f4 index, 16384 total
    const float4* p = (const float4*)partial;
    float4 s = p[idx];
#pragma unroll
    for (int k = 1; k < NSPLIT; ++k) {
        const float4 v = p[idx + k * (BATCH * OUTF / 4)];
        s.x += v.x; s.y += v.y; s.z += v.z; s.w += v.w;
    }
    ((float4*)out)[idx] = s;
}

extern "C" void kernel_launch(void* const* d_in, const int* in_sizes, int n_in,
                              void* d_out, int out_size, void* d_ws, size_t ws_size,
                              hipStream_t stream) {
    const float* x  = (const float*)d_in[0];
    const float* W  = (const float*)d_in[1];
    const float* B  = (const float*)d_in[2];
    const float* ow = (const float*)d_in[3];
    float* out  = (float*)d_out;
    float* part = (float*)d_ws;                              // 1 MiB
    float* partial = (float*)((char*)d_ws + (1u << 20));     // up to 2 MiB

    k_interf<<<dim3(512 * KSPLIT), dim3(256), 0, stream>>>(x, W, B, part);

    if (ws_size >= (3u << 20)) {
        k_proj<8, false><<<dim3(64 * 8), dim3(256), 0, stream>>>(part, ow, partial);
        k_reduce<8><<<dim3(64), dim3(256), 0, stream>>>(partial, out);
    } else if (ws_size >= (2u << 20)) {
        k_proj<4, false><<<dim3(64 * 4), dim3(256), 0, stream>>>(part, ow, partial);
        k_reduce<4><<<dim3(64), dim3(256), 0, stream>>>(partial, out);
    } else {
        hipMemsetAsync(d_out, 0, (size_t)out_size * sizeof(float), stream);
        k_proj<8, true><<<dim3(64 * 8), dim3(256), 0, stream>>>(part, ow, out);
    }
}

// Round 4
// 122.393 us; speedup vs baseline: 2.2930x; 2.2930x over previous
//
#include <hip/hip_runtime.h>
#include <math.h>

// Problem sizes (fixed by setup_inputs)
constexpr int BATCH = 64;
constexpr int IN    = 1024;
constexpr int NN    = 2048;   // num_neurons
constexpr int OUTF  = 1024;

constexpr float SCALE   = 651.8986469044033f;   // 4096 / (2*pi)
constexpr float INV4096 = 2.44140625e-4f;       // 1/4096
constexpr float SQRT2   = 1.4142135623730951f;

// ---------------- Stage 1: interference ----------------
constexpr int KSPLIT = 2;              // k-slabs -> 2 partial buffers
constexpr int KRANGE = IN / KSPLIT;    // 512 k per block
constexpr int KC     = 256;            // staged k-chunk (one wave-row = 1024B)
constexpr int PAD    = 260;            // LDS row stride: 16B-aligned, odd*4 -> conflict-free reads

// Butterfly transpose-reduction with COMPILE-TIME trip counts.
// (A runtime inner bound here defeats unrolling -> dynamic acc[] index ->
//  SROA fails -> acc lives in scratch. That was rounds 1-3's 300MB of HBM
//  scratch traffic. Template recursion keeps every index constant.)
template<int M>
__device__ __forceinline__ void butterfly(float* acc, int lane) {
    const bool hi = (lane & M) != 0;
#pragma unroll
    for (int j = 0; j < M; ++j) {
        const float send = hi ? acc[j] : acc[j + M];
        const float recv = __shfl_xor(send, M, 64);
        acc[j] = (hi ? acc[j + M] : acc[j]) + recv;
    }
    if constexpr (M > 1) butterfly<M / 2>(acc, lane);
}

// part[kslab][n][b]  (2 * 2048 * 64 floats = 1 MiB in ws)

__global__ __launch_bounds__(256)
__attribute__((amdgpu_waves_per_eu(4, 4)))   // LDS already caps at 4 blocks/CU; give RA the full 128-reg budget
void k_interf(const float* __restrict__ x, const float* __restrict__ W,
              const float* __restrict__ B, float* __restrict__ part) {
    __shared__ float xs[32 * PAD];   // 32 batch-rows x 256 k (padded) = 33.3 KB

    const int tid   = threadIdx.x;
    const int lane  = tid & 63;
    const int wv    = __builtin_amdgcn_readfirstlane(tid >> 6);   // wave id, scalar
    const int bid   = blockIdx.x;               // 1024 blocks
    const int kslab = bid & (KSPLIT - 1);
    const int n     = (bid >> 1) * 4 + wv;      // neuron handled by this wave
    const int k0    = kslab * KRANGE;
    const int r0    = wv * 8;                   // this wave stages rows r0..r0+7

#pragma unroll
    for (int h = 0; h < 2; ++h) {               // batch halves -> acc[32] in VGPRs
        float acc[32];
#pragma unroll
        for (int b = 0; b < 32; ++b) acc[b] = 0.0f;

#pragma unroll
        for (int kc = 0; kc < KRANGE; kc += KC) {
            const int kb = k0 + kc;

            // per-lane prep for 4 k values: inv = SCALE/(1+|W|), bsc = B*SCALE
            const float4 w4 = *(const float4*)&W[(size_t)n * IN + kb + 4 * lane];
            const float4 b4 = *(const float4*)&B[(size_t)n * IN + kb + 4 * lane];
            float4 inv, bsc;
            inv.x = SCALE * __builtin_amdgcn_rcpf(1.0f + fabsf(w4.x));
            inv.y = SCALE * __builtin_amdgcn_rcpf(1.0f + fabsf(w4.y));
            inv.z = SCALE * __builtin_amdgcn_rcpf(1.0f + fabsf(w4.z));
            inv.w = SCALE * __builtin_amdgcn_rcpf(1.0f + fabsf(w4.w));
            bsc.x = b4.x * SCALE;
            bsc.y = b4.y * SCALE;
            bsc.z = b4.z * SCALE;
            bsc.w = b4.w * SCALE;

            __syncthreads();   // protect xs from previous chunk's readers
            {
                // async global->LDS, zero VGPR temps: one wave-issue per row
                const float* gx = x + (size_t)(h * 32) * IN + kb;
#pragma unroll
                for (int rr = 0; rr < 8; ++rr) {
                    const int r = r0 + rr;
                    __builtin_amdgcn_global_load_lds(
                        (const __attribute__((address_space(1))) unsigned int*)
                            (gx + (size_t)r * IN + 4 * lane),
                        (__attribute__((address_space(3))) unsigned int*)&xs[r * PAD],
                        16, 0, 0);
                }
            }
            __syncthreads();   // drains vmcnt (global_load_lds) before reads

#pragma unroll
            for (int bb = 0; bb < 32; ++bb) {
                const float4 xv = *(const float4*)&xs[bb * PAD + 4 * lane];
                // s = theta*SCALE ; quantized angle (revolutions) = rint(s)/4096 ; +1/8 rev = +pi/4
                const float s0 = fmaf(xv.x, inv.x, bsc.x);
                const float s1 = fmaf(xv.y, inv.y, bsc.y);
                const float s2 = fmaf(xv.z, inv.z, bsc.z);
                const float s3 = fmaf(xv.w, inv.w, bsc.w);
                const float a0 = fmaf(__builtin_rintf(s0), INV4096, 0.125f);
                const float a1 = fmaf(__builtin_rintf(s1), INV4096, 0.125f);
                const float a2 = fmaf(__builtin_rintf(s2), INV4096, 0.125f);
                const float a3 = fmaf(__builtin_rintf(s3), INV4096, 0.125f);
                const float t0 = __builtin_amdgcn_sinf(a0);   // sin(2*pi*a)
                const float t1 = __builtin_amdgcn_sinf(a1);
                const float t2 = __builtin_amdgcn_sinf(a2);
                const float t3 = __builtin_amdgcn_sinf(a3);
                acc[bb] += (t0 + t1) + (t2 + t3);
            }
        }

        // cross-lane transpose-reduction, 32 values over 64 lanes.
        // Fold the half-wave first: lanes l and l^32 then hold identical batch sets.
#pragma unroll
        for (int j = 0; j < 32; ++j) acc[j] += __shfl_xor(acc[j], 32, 64);
        butterfly<16>(acc, lane);

        if (lane < 32)   // lane l holds batch h*32 + l
            part[((size_t)kslab * NN + n) * 64 + h * 32 + lane] = acc[0] * SQRT2;
    }
}

// ---------------- Stage 2: projection ----------------
// Block computes [64 b x 16 o] over NN/NSPLIT n, LDS-staged part, no atomics
// (atomic fallback if ws is small). grid = 64 o-tiles * NSPLIT.

template<int NSPLIT, bool ATOMIC>
__global__ __launch_bounds__(256, 4)
void k_proj(const float* __restrict__ part, const float* __restrict__ ow,
            float* __restrict__ dst) {
    __shared__ float xs[64 * 64];   // [nn][b], 16 KB

    const int tid  = threadIdx.x;
    const int lane = tid & 63;                                   // = batch b
    const int og   = __builtin_amdgcn_readfirstlane(tid >> 6);   // wave-uniform
    const int bid  = blockIdx.x;
    const int ns   = bid % NSPLIT;
    const int ot   = bid / NSPLIT;                               // 0..63
    const int o0   = ot * 16 + og * 4;
    const int NR   = NN / NSPLIT;
    const int n0   = ns * NR;

    float a0 = 0.f, a1 = 0.f, a2 = 0.f, a3 = 0.f;

    for (int c = 0; c < NR; c += 64) {
        const int nb = n0 + c;
        __syncthreads();
        {   // stage 64n x 64b, summing the two k-slabs
            const float4* s0 = (const float4*)(part + (size_t)nb * 64);
            const float4* s1 = (const float4*)(part + (size_t)NN * 64 + (size_t)nb * 64);
            float4* xd = (float4*)xs;
#pragma unroll
            for (int r = 0; r < 4; ++r) {
                const int j = tid + 256 * r;
                const float4 u = s0[j];
                const float4 v = s1[j];
                float4 s; s.x = u.x + v.x; s.y = u.y + v.y; s.z = u.z + v.z; s.w = u.w + v.w;
                xd[j] = s;
            }
        }
        __syncthreads();

        const float* w0 = ow + (size_t)(o0 + 0) * NN + nb;
        const float* w1 = ow + (size_t)(o0 + 1) * NN + nb;
        const float* w2 = ow + (size_t)(o0 + 2) * NN + nb;
        const float* w3 = ow + (size_t)(o0 + 3) * NN + nb;
#pragma unroll 4
        for (int nn = 0; nn < 64; nn += 4) {
            const float4 wa = *(const float4*)(w0 + nn);
            const float4 wb = *(const float4*)(w1 + nn);
            const float4 wc = *(const float4*)(w2 + nn);
            const float4 wd = *(const float4*)(w3 + nn);
            const float v0 = xs[(nn + 0) * 64 + lane];
            const float v1 = xs[(nn + 1) * 64 + lane];
            const float v2 = xs[(nn + 2) * 64 + lane];
            const float v3 = xs[(nn + 3) * 64 + lane];
            a0 = fmaf(v0, wa.x, a0); a0 = fmaf(v1, wa.y, a0);
            a0 = fmaf(v2, wa.z, a0); a0 = fmaf(v3, wa.w, a0);
            a1 = fmaf(v0, wb.x, a1); a1 = fmaf(v1, wb.y, a1);
            a1 = fmaf(v2, wb.z, a1); a1 = fmaf(v3, wb.w, a1);
            a2 = fmaf(v0, wc.x, a2); a2 = fmaf(v1, wc.y, a2);
            a2 = fmaf(v2, wc.z, a2); a2 = fmaf(v3, wc.w, a2);
            a3 = fmaf(v0, wd.x, a3); a3 = fmaf(v1, wd.y, a3);
            a3 = fmaf(v2, wd.z, a3); a3 = fmaf(v3, wd.w, a3);
        }
    }

    if (ATOMIC) {
        atomicAdd(&dst[(size_t)lane * OUTF + o0 + 0], a0);
        atomicAdd(&dst[(size_t)lane * OUTF + o0 + 1], a1);
        atomicAdd(&dst[(size_t)lane * OUTF + o0 + 2], a2);
        atomicAdd(&dst[(size_t)lane * OUTF + o0 + 3], a3);
    } else {
        float4 r; r.x = a0; r.y = a1; r.z = a2; r.w = a3;
        *(float4*)&dst[((size_t)ns * 64 + lane) * OUTF + o0] = r;
    }
}

template<int NSPLIT>
__global__ __launch_bounds__(256)
void k_reduce(const float* __restrict__ partial, float* __restrict__ out) {
    const int idx = blockIdx.x * 256 + threadIdx.x;   // f4 index, 16384 total
    const float4* p = (const float4*)partial;
    float4 s = p[idx];
#pragma unroll
    for (int k = 1; k < NSPLIT; ++k) {
        const float4 v = p[idx + k * (BATCH * OUTF / 4)];
        s.x += v.x; s.y += v.y; s.z += v.z; s.w += v.w;
    }
    ((float4*)out)[idx] = s;
}

extern "C" void kernel_launch(void* const* d_in, const int* in_sizes, int n_in,
                              void* d_out, int out_size, void* d_ws, size_t ws_size,
                              hipStream_t stream) {
    const float* x  = (const float*)d_in[0];
    const float* W  = (const float*)d_in[1];
    const float* B  = (const float*)d_in[2];
    const float* ow = (const float*)d_in[3];
    float* out  = (float*)d_out;
    float* part = (float*)d_ws;                              // 1 MiB
    float* partial = (float*)((char*)d_ws + (1u << 20));     // up to 2 MiB

    k_interf<<<dim3(512 * KSPLIT), dim3(256), 0, stream>>>(x, W, B, part);

    if (ws_size >= (3u << 20)) {
        k_proj<8, false><<<dim3(64 * 8), dim3(256), 0, stream>>>(part, ow, partial);
        k_reduce<8><<<dim3(64), dim3(256), 0, stream>>>(partial, out);
    } else if (ws_size >= (2u << 20)) {
        k_proj<4, false><<<dim3(64 * 4), dim3(256), 0, stream>>>(part, ow, partial);
        k_reduce<4><<<dim3(64), dim3(256), 0, stream>>>(partial, out);
    } else {
        hipMemsetAsync(d_out, 0, (size_t)out_size * sizeof(float), stream);
        k_proj<8, true><<<dim3(64 * 8), dim3(256), 0, stream>>>(part, ow, out);
    }
}